// Round 2
// baseline (286.867 us; speedup 1.0000x reference)
//
#include <hip/hip_runtime.h>
#include <stdint.h>

typedef unsigned long long u64;
typedef unsigned int u32;
typedef int v4i __attribute__((ext_vector_type(4)));
typedef int v16i __attribute__((ext_vector_type(16)));
typedef short s4v __attribute__((ext_vector_type(4)));
typedef short s8v __attribute__((ext_vector_type(8)));
typedef float f4v __attribute__((ext_vector_type(4)));

#define B_    32
#define CIN   256
#define COUT  256
#define H_    56
#define W_    56
#define HW    3136            // H_*W_
#define NPOS  100352          // B_*HW
#define HBLK  28              // H_/2  (two output rows per block)
#define NPACKBLK 392          // (NPOS/4/256) * 4 j-chunks

// ---- workspace layout (bytes) ----
// 0        : Bfrag i8[72*8*64*16]     589824   (MFMA B-operand, fragment-order)
// 589824   : alpha f32[256]           1024
// 590848   : ssum  i32[256]           1024
// 591872   : qsum  u64[256]           2048
// 593920   : xbits u64[NPOS*4]        3211264  (ends 3805184)
// 3805184  : S     s16[256][NPOS] CHW-major  51380224 (ends 55185408)

// ---------------- Kernel 1: prep (x bitpack ∪ weight prep), grid-partitioned ----------------
__global__ __launch_bounds__(256) void k_prep(
    const float* __restrict__ x,     // [B, C, H, W]
    const float* __restrict__ wgt,   // [O=256, I=256, 3, 3]
    u64* __restrict__ xbits,         // [NPOS][4]
    int8_t* __restrict__ Bfrag,      // [kk=72][nt=8][lane=64][16]
    float* __restrict__ alpha,
    int* __restrict__ ssum,
    unsigned long long* __restrict__ qsum)
{
    const int tid = threadIdx.x;

    if (blockIdx.x < NPACKBLK) {
        // ---- pack sign(x): 4 positions per thread via float4 (16B/lane coalesced) ----
        const int j = blockIdx.x / 98;                   // channel chunk
        const int p4 = (blockIdx.x - j * 98) * 256 + tid;
        const int pos0 = p4 * 4;                          // HW % 4 == 0 -> no b crossing
        const int b = pos0 / HW;
        const int hw = pos0 - b * HW;
        const float* xp = x + (size_t)b * CIN * HW + (size_t)j * 64 * HW + hw;
        u64 b0 = 0, b1 = 0, b2 = 0, b3 = 0;
#pragma unroll 8
        for (int k = 0; k < 64; ++k) {
            const float4 v = *(const float4*)(xp + (size_t)k * HW);
            b0 |= (u64)(v.x > 0.0f) << k;
            b1 |= (u64)(v.y > 0.0f) << k;
            b2 |= (u64)(v.z > 0.0f) << k;
            b3 |= (u64)(v.w > 0.0f) << k;
        }
        xbits[(size_t)pos0 * 4 + j] = b0;
        xbits[(size_t)(pos0 + 1) * 4 + j] = b1;
        xbits[(size_t)(pos0 + 2) * 4 + j] = b2;
        xbits[(size_t)(pos0 + 3) * 4 + j] = b3;
        return;
    }

    // ---- weight prep: mean-center, clip, alpha, Bfrag bytes; zero stats ----
    const int o = blockIdx.x - NPACKBLK;
    const int i = tid;                 // input channel
    const int wave = i >> 6, lane = i & 63;
    __shared__ float sred[4][12];

    if (i == 0) { ssum[o] = 0; qsum[o] = 0ULL; }

    float w9[9];
#pragma unroll
    for (int t = 0; t < 9; ++t) w9[t] = wgt[(o * 256 + i) * 9 + t];

    float m[9];
#pragma unroll
    for (int t = 0; t < 9; ++t) m[t] = w9[t];
#pragma unroll
    for (int s = 1; s < 64; s <<= 1)
#pragma unroll
        for (int t = 0; t < 9; ++t) m[t] += __shfl_xor(m[t], s, 64);
    if (lane == 0) {
#pragma unroll
        for (int t = 0; t < 9; ++t) sred[wave][t] = m[t];
    }
    __syncthreads();
#pragma unroll
    for (int t = 0; t < 9; ++t)
        m[t] = (sred[0][t] + sred[1][t] + sred[2][t] + sred[3][t]) * (1.0f / 256.0f);

    float wc[9];
    float asum = 0.0f;
#pragma unroll
    for (int t = 0; t < 9; ++t) {
        float v = w9[t] - m[t];
        v = fminf(fmaxf(v, -1.0f), 1.0f);
        wc[t] = v;
        asum += fabsf(v);
    }
#pragma unroll
    for (int s = 1; s < 64; s <<= 1) asum += __shfl_xor(asum, s, 64);
    __syncthreads();
    if (lane == 0) sred[wave][9] = asum;
    __syncthreads();
    if (i == 0)
        alpha[o] = (sred[0][9] + sred[1][9] + sred[2][9] + sred[3][9]) * (1.0f / 2304.0f);

    // Bfrag[kk][nt][l][j]: value = sign(wc) for k = kk*32 + (l>>5)*16 + j,
    // tap = k>>8, c = k&255; n = nt*32 + (l&31) = o.
#pragma unroll
    for (int t = 0; t < 9; ++t) {
        const int8_t sv = (wc[t] > 0.0f) ? (int8_t)1 : (int8_t)-1;
        const size_t addr =
            ((size_t)((t * 8 + (i >> 5)) * 8 + (o >> 5)) * 64
             + (size_t)(((i >> 4) & 1) * 32 + (o & 31))) * 16 + (i & 15);
        Bfrag[addr] = sv;
    }
}

// ---------------- Kernel 2: implicit-GEMM i8 MFMA conv -> S ([C][NPOS] s16) + stats ----------------
// Block = (b, h-pair): M=128 positions (2 output rows of 56), N=256 channels,
// K=2304 (72 steps of 32). Each wave does 4 A-tiles x 2 B-slices = 8 MFMA/kk,
// reusing the SAME 2KB of B across 128 M (halves per-CU L2->CU B stream).
// A staged in LDS as ±1 bytes over 4 input rows (58 cols; wp=0/57 zero pad;
// M-pad rows clamp to col 57 — results discarded). Granule rotation (g+wp)&15
// breaks the 256B-stride bank pattern. B streamed from Bfrag (L2-resident).
// Epilogue: C-layout gives 4 CONSECUTIVE m per reg-quad -> pack short4 and
// store channel-major S[C][NPOS]: 8B stores, 224B/channel/block runs merged
// in L2. This removes the NHWC->NCHW transpose from kb_apply entirely.
#define MFMA_I8(acc, a, b) \
    asm volatile("v_mfma_i32_32x32x32_i8 %0, %1, %2, %0" : "+a"(acc) : "v"(a), "v"(b))

__global__ __launch_bounds__(256, 2) void kc_mfma(
    const u64* __restrict__ xbits,
    const int8_t* __restrict__ Bfrag,
    short* __restrict__ S,           // [256][NPOS]
    int* __restrict__ ssum,
    unsigned long long* __restrict__ qsum)
{
    const int blk = blockIdx.x;        // (b, h-pair)
    const int b = blk / HBLK;
    const int h0 = (blk - b * HBLK) * 2;
    const int tid = threadIdx.x;

    __shared__ u32 ldsb[4 * 58 * 64];  // 59392 B -> 2 blocks/CU

    for (int it = tid; it < 4 * 58 * 16; it += 256) {
        const int r = it / 928;              // 58*16, r = 0..3 -> input rows h0-1..h0+2
        const int rem = it - r * 928;
        const int wp = rem >> 4;
        const int g = rem & 15;
        const int hr = h0 - 1 + r;
        const int w_in = wp - 1;
        const bool inb = (hr >= 0) && (hr < H_) && (w_in >= 0) && (w_in < W_);
        u32 chunk16 = 0;
        if (inb) {
            const u64 word = xbits[((size_t)(b * HW + hr * W_ + w_in)) * 4 + (g >> 2)];
            chunk16 = (u32)(word >> ((g & 3) * 16)) & 0xFFFFu;
        }
        u32 out4[4];
#pragma unroll
        for (int d = 0; d < 4; ++d) {
            const u32 nib = (chunk16 >> (4 * d)) & 0xFu;
            const u32 m1 = (nib * 0x00204081u) & 0x01010101u;   // bit u -> byte u
            const u32 inv = m1 ^ 0x01010101u;
            out4[d] = inb ? (0x01010101u ^ (inv * 0xFEu)) : 0u; // 1->+1, 0->-1, OOB->0
        }
        const int gs = (g + wp) & 15;
        u32* dst = &ldsb[((r * 58 + wp) << 6) + gs * 4];
        dst[0] = out4[0]; dst[1] = out4[1]; dst[2] = out4[2]; dst[3] = out4[3];
    }
    __syncthreads();

    const int m0 = tid & 31;           // lane&31: M row within 32-tile AND output-channel low bits
    const int lh = (tid >> 5) & 1;     // k-half selector
    const int wv = tid >> 6;           // wave id: N cols 64*wv .. 64*wv+63
    const int8_t* smem = (const int8_t*)ldsb;
    const int8_t* Bp = Bfrag + (size_t)(tid & 63) * 16;

    // mt = 0..3: output row h0 + (mt>>1), w-tile (mt&1)
    auto ldA = [&](int kk, int mt) -> v4i {
        const int tap = kk >> 3, s = kk & 7;   // constant after unroll
        const int dh = tap / 3;
        const int dw = tap - dh * 3;
        const int r = (mt >> 1) + dh;
        const int wpm = min((mt & 1) * 32 + m0 + dw, 57);
        const int gs = (2 * s + lh + wpm) & 15;
        const int addr = ((r * 58 + wpm) << 8) + (gs << 4);
        return *(const v4i*)(smem + addr);
    };
    auto ldB = [&](int kk, int ntl) -> v4i {
        const size_t off = (size_t)((kk * 8) + wv * 2 + ntl) * 1024;
        return *(const v4i*)(Bp + off);
    };

    v16i acc[4][2] = {};
    v4i A[4][2], Bb[2][2];

#pragma unroll
    for (int mt = 0; mt < 4; ++mt) A[mt][0] = ldA(0, mt);
    Bb[0][0] = ldB(0, 0);
    Bb[1][0] = ldB(0, 1);

#pragma unroll
    for (int kk = 0; kk < 72; ++kk) {
        const int cur = kk & 1, nxt = cur ^ 1;
        if (kk < 71) {
#pragma unroll
            for (int mt = 0; mt < 4; ++mt) A[mt][nxt] = ldA(kk + 1, mt);
            Bb[0][nxt] = ldB(kk + 1, 0);
            Bb[1][nxt] = ldB(kk + 1, 1);
        }
#pragma unroll
        for (int mt = 0; mt < 4; ++mt) {
            MFMA_I8(acc[mt][0], A[mt][cur], Bb[0][cur]);
            MFMA_I8(acc[mt][1], A[mt][cur], Bb[1][cur]);
        }
    }

    // drain MFMA pipe before AGPR reads (compiler is blind to asm latency)
    asm volatile("s_nop 7\n\ts_nop 7\n\ts_nop 7"
                 : "+a"(acc[0][0]), "+a"(acc[0][1]), "+a"(acc[1][0]), "+a"(acc[1][1]),
                   "+a"(acc[2][0]), "+a"(acc[2][1]), "+a"(acc[3][0]), "+a"(acc[3][1]));

    // C/D layout: n = nt*32 + (lane&31); m-in-tile = (reg&3) + 8*(reg>>2) + 4*lh.
    // Reg-quad q (regs 4q..4q+3) -> 4 consecutive w at 8q + 4lh + j: pack short4.
    const int n0 = wv * 64 + m0;
    int s0 = 0, s1 = 0, q0 = 0, q1 = 0;

#pragma unroll
    for (int mt = 0; mt < 4; ++mt) {
        const int h = h0 + (mt >> 1);
        const size_t rowb = (size_t)b * HW + (size_t)h * W_ + ((mt & 1) << 5) + (lh << 2);
        const int nq = (mt & 1) ? 3 : 4;   // odd w-tiles: w 32..55 only (regs < 12)
#pragma unroll
        for (int q = 0; q < nq; ++q) {
            s4v pk0, pk1;
#pragma unroll
            for (int j = 0; j < 4; ++j) {
                const int v0 = acc[mt][0][4 * q + j];
                const int v1 = acc[mt][1][4 * q + j];
                s0 += v0; q0 += v0 * v0; s1 += v1; q1 += v1 * v1;
                pk0[j] = (short)v0;
                pk1[j] = (short)v1;
            }
            *(s4v*)(S + (size_t)n0 * NPOS + rowb + 8 * q) = pk0;
            *(s4v*)(S + (size_t)(n0 + 32) * NPOS + rowb + 8 * q) = pk1;
        }
    }

    s0 += __shfl_xor(s0, 32, 64); q0 += __shfl_xor(q0, 32, 64);
    s1 += __shfl_xor(s1, 32, 64); q1 += __shfl_xor(q1, 32, 64);
    if (lh == 0) {
        atomicAdd(&ssum[n0], s0);
        atomicAdd(&qsum[n0], (unsigned long long)(long long)q0);
        atomicAdd(&ssum[n0 + 32], s1);
        atomicAdd(&qsum[n0 + 32], (unsigned long long)(long long)q1);
    }
}

// ---------------- Kernel 3: BN finalize + ReLU, pure streaming ----------------
// S is [C][B][HW]; out is [B][C][HW]. One block per (c,b) plane: contiguous
// 6272B short8 reads, contiguous 12544B float4 writes. No LDS, no transpose.
__global__ __launch_bounds__(256) void kb_apply(
    const short* __restrict__ S,
    const int* __restrict__ ssum,
    const unsigned long long* __restrict__ qsum,
    const float* __restrict__ alpha,
    const float* __restrict__ gamma,
    const float* __restrict__ beta,
    float* __restrict__ out)
{
    const int blk = blockIdx.x;              // c*32 + b  (consecutive blocks stream S)
    const int c = blk >> 5;
    const int b = blk & 31;

    // BN finalize: block-uniform scalars (conv bias cancels exactly in training BN)
    const double N = (double)NPOS;
    const double meanS = (double)ssum[c] / N;
    const double varS = (double)qsum[c] / N - meanS * meanS;
    const double a = (double)alpha[c];
    const double rstd = 1.0 / sqrt(a * a * varS + 1e-5);
    const double g = (double)gamma[c];
    const float scale = (float)(g * a * rstd);
    const float shift = (float)((double)beta[c] - g * a * meanS * rstd);

    const s8v* src = (const s8v*)(S + (size_t)c * NPOS + (size_t)b * HW);
    float* dst = out + ((size_t)(b * COUT + c)) * HW;

    for (int idx = threadIdx.x; idx < HW / 8; idx += 256) {   // 392 short8 chunks
        const s8v v = src[idx];
        f4v o0, o1;
#pragma unroll
        for (int j = 0; j < 4; ++j)
            o0[j] = fmaxf(fmaf((float)v[j], scale, shift), 0.0f);
#pragma unroll
        for (int j = 0; j < 4; ++j)
            o1[j] = fmaxf(fmaf((float)v[4 + j], scale, shift), 0.0f);
        *(f4v*)(dst + idx * 8) = o0;
        *(f4v*)(dst + idx * 8 + 4) = o1;
    }
}

extern "C" void kernel_launch(void* const* d_in, const int* in_sizes, int n_in,
                              void* d_out, int out_size, void* d_ws, size_t ws_size,
                              hipStream_t stream) {
    const float* x     = (const float*)d_in[0];   // [32,256,56,56]
    const float* wgt   = (const float*)d_in[1];   // [256,256,3,3]
    // d_in[2] = bias: cancels exactly in BN, unused
    const float* gamma = (const float*)d_in[3];
    const float* beta  = (const float*)d_in[4];
    float* out = (float*)d_out;

    char* ws = (char*)d_ws;
    int8_t* Bfrag = (int8_t*)(ws + 0);
    float* alpha = (float*)(ws + 589824);
    int*   ssum  = (int*)(ws + 590848);
    unsigned long long* qsum = (unsigned long long*)(ws + 591872);
    u64*   xbits = (u64*)(ws + 593920);
    short* Sarr  = (short*)(ws + 3805184);

    k_prep<<<NPACKBLK + 256, 256, 0, stream>>>(x, wgt, xbits, Bfrag, alpha, ssum, qsum);
    kc_mfma<<<B_ * HBLK, 256, 0, stream>>>(xbits, Bfrag, Sarr, ssum, qsum);
    kb_apply<<<COUT * B_, 256, 0, stream>>>(Sarr, ssum, qsum, alpha, gamma, beta, out);
}

// Round 3
// 278.010 us; speedup vs baseline: 1.0319x; 1.0319x over previous
//
#include <hip/hip_runtime.h>
#include <stdint.h>

typedef unsigned long long u64;
typedef unsigned int u32;
typedef int v4i __attribute__((ext_vector_type(4)));
typedef int v16i __attribute__((ext_vector_type(16)));
typedef short s4v __attribute__((ext_vector_type(4)));
typedef short s8v __attribute__((ext_vector_type(8)));
typedef float f4v __attribute__((ext_vector_type(4)));
typedef u64 u64x2 __attribute__((ext_vector_type(2)));

#define B_    32
#define CIN   256
#define COUT  256
#define H_    56
#define W_    56
#define HW    3136            // H_*W_
#define NPOS  100352          // B_*HW
#define HBLK  28              // H_/2  (two output rows per block)
#define NPACKBLK 392          // (NPOS/4/256) * 4 j-chunks

// ---- workspace layout (bytes) ----
// 0        : Bfrag i8[wv=4][kk=72][ntl=2][64][16]  589824  (per-wave contiguous streams)
// 589824   : alpha f32[256]           1024
// 590848   : ssum  i32[256]           1024
// 591872   : qsum  u64[256]           2048
// 593920   : xbits u64[4][NPOS]       3211264  (4 channel-planes; ends 3805184)
// 3805184  : S     s16[256][NPOS] CHW-major  51380224 (ends 55185408)

// ---------------- Kernel 1: prep (x bitpack ∪ weight prep), grid-partitioned ----------------
__global__ __launch_bounds__(256) void k_prep(
    const float* __restrict__ x,     // [B, C, H, W]
    const float* __restrict__ wgt,   // [O=256, I=256, 3, 3]
    u64* __restrict__ xbits,         // [4][NPOS]
    int8_t* __restrict__ Bfrag,      // [wv][kk][ntl][lane][16]
    float* __restrict__ alpha,
    int* __restrict__ ssum,
    unsigned long long* __restrict__ qsum)
{
    const int tid = threadIdx.x;

    if (blockIdx.x < NPACKBLK) {
        // ---- pack sign(x): 4 positions per thread via float4 (16B/lane coalesced) ----
        const int j = blockIdx.x / 98;                   // channel chunk (plane)
        const int p4 = (blockIdx.x - j * 98) * 256 + tid;
        const int pos0 = p4 * 4;                          // HW % 4 == 0 -> no b crossing
        const int b = pos0 / HW;
        const int hw = pos0 - b * HW;
        const float* xp = x + (size_t)b * CIN * HW + (size_t)j * 64 * HW + hw;
        u64 b0 = 0, b1 = 0, b2 = 0, b3 = 0;
#pragma unroll 8
        for (int k = 0; k < 64; ++k) {
            const float4 v = *(const float4*)(xp + (size_t)k * HW);
            b0 |= (u64)(v.x > 0.0f) << k;
            b1 |= (u64)(v.y > 0.0f) << k;
            b2 |= (u64)(v.z > 0.0f) << k;
            b3 |= (u64)(v.w > 0.0f) << k;
        }
        // plane layout: 32B contiguous per thread, 2KB per wave
        u64* xp4 = xbits + (size_t)j * NPOS + pos0;
        *(u64x2*)(xp4)     = u64x2{b0, b1};
        *(u64x2*)(xp4 + 2) = u64x2{b2, b3};
        return;
    }

    // ---- weight prep: mean-center, clip, alpha, Bfrag bytes; zero stats ----
    const int o = blockIdx.x - NPACKBLK;
    const int i = tid;                 // input channel
    const int wave = i >> 6, lane = i & 63;
    __shared__ float sred[4][12];

    if (i == 0) { ssum[o] = 0; qsum[o] = 0ULL; }

    float w9[9];
#pragma unroll
    for (int t = 0; t < 9; ++t) w9[t] = wgt[(o * 256 + i) * 9 + t];

    float m[9];
#pragma unroll
    for (int t = 0; t < 9; ++t) m[t] = w9[t];
#pragma unroll
    for (int s = 1; s < 64; s <<= 1)
#pragma unroll
        for (int t = 0; t < 9; ++t) m[t] += __shfl_xor(m[t], s, 64);
    if (lane == 0) {
#pragma unroll
        for (int t = 0; t < 9; ++t) sred[wave][t] = m[t];
    }
    __syncthreads();
#pragma unroll
    for (int t = 0; t < 9; ++t)
        m[t] = (sred[0][t] + sred[1][t] + sred[2][t] + sred[3][t]) * (1.0f / 256.0f);

    float wc[9];
    float asum = 0.0f;
#pragma unroll
    for (int t = 0; t < 9; ++t) {
        float v = w9[t] - m[t];
        v = fminf(fmaxf(v, -1.0f), 1.0f);
        wc[t] = v;
        asum += fabsf(v);
    }
#pragma unroll
    for (int s = 1; s < 64; s <<= 1) asum += __shfl_xor(asum, s, 64);
    __syncthreads();
    if (lane == 0) sred[wave][9] = asum;
    __syncthreads();
    if (i == 0)
        alpha[o] = (sred[0][9] + sred[1][9] + sred[2][9] + sred[3][9]) * (1.0f / 2304.0f);

    // Bfrag[wv][kk][ntl][l][j]: value = sign(wc) for k = kk*32 + (l>>5)*16 + j,
    // tap = k>>8, c = k&255; out-channel o = (wv*2+ntl)*32 + (l&31).
#pragma unroll
    for (int t = 0; t < 9; ++t) {
        const int8_t sv = (wc[t] > 0.0f) ? (int8_t)1 : (int8_t)-1;
        const int kk = t * 8 + (i >> 5);
        const size_t addr =
            ((((size_t)(o >> 6) * 72 + kk) * 2 + ((o >> 5) & 1)) * 64
             + (size_t)(((i >> 4) & 1) * 32 + (o & 31))) * 16 + (i & 15);
        Bfrag[addr] = sv;
    }
}

// ---------------- Kernel 2: implicit-GEMM i8 MFMA conv -> S ([C][NPOS] s16) + stats ----------------
// Block = (b, h-pair): M=128 positions (2 output rows of 56), N=256 channels,
// K=2304 (72 steps of 32). Each wave: 4 A-tiles x 2 B-slices = 8 MFMA/kk,
// reusing the SAME 2KB of B across 128 M (B-stream 16KB/kk/CU, under MFMA time).
// A staged in LDS as ±1 bytes over 4 input rows (58 cols; wp=0/57 zero pad;
// M-pad lanes clamp to col 57 — results discarded). XOR granule swizzle
// (g ^ (wp&15)) breaks the 256B-stride bank pattern AND makes the per-kk read
// address a single v_xor with a literal: addr = P_mt ^ (s<<5), P_mt CSE'd per
// 8-kk tap group. B streamed from per-wave-contiguous Bfrag (L2-resident).
// s_setprio(1) wraps the MFMA cluster (waves are barrier-free/phase-slipped).
// Epilogue: acc -> LDS (A-buffer dead, 256ch x 116sh stride-232B = conflict-free)
// -> 224B-contiguous dwordx4 runs per channel into channel-major S.
#define MFMA_I8(acc, a, b) \
    asm volatile("v_mfma_i32_32x32x32_i8 %0, %1, %2, %0" : "+a"(acc) : "v"(a), "v"(b))

__global__ __launch_bounds__(256, 2) void kc_mfma(
    const u64* __restrict__ xbits,   // [4][NPOS]
    const int8_t* __restrict__ Bfrag,
    short* __restrict__ S,           // [256][NPOS]
    int* __restrict__ ssum,
    unsigned long long* __restrict__ qsum)
{
    const int blk = blockIdx.x;        // (b, h-pair)
    const int b = blk / HBLK;
    const int h0 = (blk - b * HBLK) * 2;
    const int tid = threadIdx.x;

    __shared__ u32 ldsb[4 * 58 * 64];  // 59392 B -> 2 blocks/CU

    for (int it = tid; it < 4 * 58 * 16; it += 256) {
        const int r = it / 928;              // 58*16, r = 0..3 -> input rows h0-1..h0+2
        const int rem = it - r * 928;
        const int wp = rem >> 4;
        const int g = rem & 15;
        const int hr = h0 - 1 + r;
        const int w_in = wp - 1;
        const bool inb = (hr >= 0) && (hr < H_) && (w_in >= 0) && (w_in < W_);
        u32 chunk16 = 0;
        if (inb) {
            const u64 word = xbits[(size_t)(g >> 2) * NPOS
                                   + (size_t)(b * HW + hr * W_ + w_in)];
            chunk16 = (u32)(word >> ((g & 3) * 16)) & 0xFFFFu;
        }
        u32 out4[4];
#pragma unroll
        for (int d = 0; d < 4; ++d) {
            const u32 nib = (chunk16 >> (4 * d)) & 0xFu;
            const u32 m1 = (nib * 0x00204081u) & 0x01010101u;   // bit u -> byte u
            const u32 inv = m1 ^ 0x01010101u;
            out4[d] = inb ? (0x01010101u ^ (inv * 0xFEu)) : 0u; // 1->+1, 0->-1, OOB->0
        }
        const int gs = (g ^ wp) & 15;        // XOR granule swizzle
        u32* dst = &ldsb[((r * 58 + wp) << 6) + gs * 4];
        dst[0] = out4[0]; dst[1] = out4[1]; dst[2] = out4[2]; dst[3] = out4[3];
    }
    __syncthreads();

    const int m0 = tid & 31;           // M row within 32-tile / channel low bits
    const int lh = (tid >> 5) & 1;     // k-half selector
    const int wv = tid >> 6;           // wave id: N cols 64*wv .. 64*wv+63
    const int8_t* smem = (const int8_t*)ldsb;
    const int8_t* Bp = Bfrag + (size_t)wv * 147456 + (size_t)(tid & 63) * 16;

    // mt = 0..3: output row h0 + (mt>>1), w-tile (mt&1)
    auto ldA = [&](int kk, int mt) -> v4i {
        const int tap = kk >> 3, s = kk & 7;   // constants after unroll
        const int dh = tap / 3;
        const int dw = tap - dh * 3;
        const int r = (mt >> 1) + dh;
        // even w-tiles: m0+dw <= 33 < 58, no clamp needed
        const int wpm = (mt & 1) ? min(32 + m0 + dw, 57) : (m0 + dw);
        const int P = ((r * 58 + wpm) << 8) + ((((wpm & 15) ^ lh)) << 4); // CSE per tap
        return *(const v4i*)(smem + (P ^ (s << 5)));   // 1 v_xor per kk
    };
    auto ldB = [&](int kk, int ntl) -> v4i {
        return *(const v4i*)(Bp + (size_t)kk * 2048 + ntl * 1024);
    };

    v16i acc[4][2] = {};
    v4i A[4][2], Bb[2][2];

#pragma unroll
    for (int mt = 0; mt < 4; ++mt) A[mt][0] = ldA(0, mt);
    Bb[0][0] = ldB(0, 0);
    Bb[1][0] = ldB(0, 1);

#pragma unroll
    for (int kk = 0; kk < 72; ++kk) {
        const int cur = kk & 1, nxt = cur ^ 1;
        if (kk < 71) {
#pragma unroll
            for (int mt = 0; mt < 4; ++mt) A[mt][nxt] = ldA(kk + 1, mt);
            Bb[0][nxt] = ldB(kk + 1, 0);
            Bb[1][nxt] = ldB(kk + 1, 1);
        }
        __builtin_amdgcn_s_setprio(1);
#pragma unroll
        for (int mt = 0; mt < 4; ++mt) {
            MFMA_I8(acc[mt][0], A[mt][cur], Bb[0][cur]);
            MFMA_I8(acc[mt][1], A[mt][cur], Bb[1][cur]);
        }
        __builtin_amdgcn_s_setprio(0);
    }

    // drain MFMA pipe before AGPR reads (compiler is blind to asm latency)
    asm volatile("s_nop 7\n\ts_nop 7\n\ts_nop 7"
                 : "+a"(acc[0][0]), "+a"(acc[0][1]), "+a"(acc[1][0]), "+a"(acc[1][1]),
                   "+a"(acc[2][0]), "+a"(acc[2][1]), "+a"(acc[3][0]), "+a"(acc[3][1]));

    // ---- epilogue: stats + pack acc into LDS (A-buffer dead), then coalesced copy ----
    // C/D layout: n = nt*32 + (lane&31); m-in-tile = (reg&3) + 8*(reg>>2) + 4*lh.
    const int n0 = wv * 64 + m0;
    int s0 = 0, s1 = 0, q0 = 0, q1 = 0;

    __syncthreads();                        // all A ds_reads retired; reuse ldsb
    short* eP = (short*)ldsb;               // [c=256][116 shorts] stride 232B

#pragma unroll
    for (int mt = 0; mt < 4; ++mt) {
        const int posb = (mt >> 1) * 56 + ((mt & 1) << 5) + (lh << 2);
        const int nq = (mt & 1) ? 3 : 4;    // odd w-tiles: w 32..55 only (regs < 12)
#pragma unroll
        for (int q = 0; q < nq; ++q) {
            s4v pk0, pk1;
#pragma unroll
            for (int j = 0; j < 4; ++j) {
                const int v0 = acc[mt][0][4 * q + j];
                const int v1 = acc[mt][1][4 * q + j];
                s0 += v0; q0 += v0 * v0; s1 += v1; q1 += v1 * v1;
                pk0[j] = (short)v0;
                pk1[j] = (short)v1;
            }
            const int pq = posb + 8 * q;    // position within the 112-run (8-aligned-ish)
            *(s4v*)((char*)eP + n0 * 232 + pq * 2) = pk0;
            *(s4v*)((char*)eP + (n0 + 32) * 232 + pq * 2) = pk1;
        }
    }
    __syncthreads();

    // copy out: per channel a contiguous 224B run (112 shorts = rows h0,h0+1)
    {
        const int l = tid & 63;
        if (l < 56) {
            const int ch2 = l / 14;          // 4 channels x 14 lanes = 224B each
            const int ii = l - ch2 * 14;
            const size_t posb2 = (size_t)b * HW + (size_t)h0 * W_;
#pragma unroll
            for (int t2 = 0; t2 < 16; ++t2) {
                const int cg = wv * 64 + t2 * 4 + ch2;
                const v4i val = *(const v4i*)((const char*)eP + cg * 232 + ii * 16);
                *(v4i*)(S + (size_t)cg * NPOS + posb2 + ii * 8) = val;
            }
        }
    }

    s0 += __shfl_xor(s0, 32, 64); q0 += __shfl_xor(q0, 32, 64);
    s1 += __shfl_xor(s1, 32, 64); q1 += __shfl_xor(q1, 32, 64);
    if (lh == 0) {
        atomicAdd(&ssum[n0], s0);
        atomicAdd(&qsum[n0], (unsigned long long)(long long)q0);
        atomicAdd(&ssum[n0 + 32], s1);
        atomicAdd(&qsum[n0 + 32], (unsigned long long)(long long)q1);
    }
}

// ---------------- Kernel 3: BN finalize + ReLU, pure streaming ----------------
// S is [C][B][HW]; out is [B][C][HW]. One block per (c,b) plane: contiguous
// short8 reads, contiguous float4 writes. No LDS, no transpose.
__global__ __launch_bounds__(256) void kb_apply(
    const short* __restrict__ S,
    const int* __restrict__ ssum,
    const unsigned long long* __restrict__ qsum,
    const float* __restrict__ alpha,
    const float* __restrict__ gamma,
    const float* __restrict__ beta,
    float* __restrict__ out)
{
    const int blk = blockIdx.x;              // c*32 + b  (consecutive blocks stream S)
    const int c = blk >> 5;
    const int b = blk & 31;

    // BN finalize: block-uniform scalars (conv bias cancels exactly in training BN)
    const double N = (double)NPOS;
    const double meanS = (double)ssum[c] / N;
    const double varS = (double)qsum[c] / N - meanS * meanS;
    const double a = (double)alpha[c];
    const double rstd = 1.0 / sqrt(a * a * varS + 1e-5);
    const double g = (double)gamma[c];
    const float scale = (float)(g * a * rstd);
    const float shift = (float)((double)beta[c] - g * a * meanS * rstd);

    const s8v* src = (const s8v*)(S + (size_t)c * NPOS + (size_t)b * HW);
    float* dst = out + ((size_t)(b * COUT + c)) * HW;

    for (int idx = threadIdx.x; idx < HW / 8; idx += 256) {   // 392 short8 chunks
        const s8v v = src[idx];
        f4v o0, o1;
#pragma unroll
        for (int j = 0; j < 4; ++j)
            o0[j] = fmaxf(fmaf((float)v[j], scale, shift), 0.0f);
#pragma unroll
        for (int j = 0; j < 4; ++j)
            o1[j] = fmaxf(fmaf((float)v[4 + j], scale, shift), 0.0f);
        *(f4v*)(dst + idx * 8) = o0;
        *(f4v*)(dst + idx * 8 + 4) = o1;
    }
}

extern "C" void kernel_launch(void* const* d_in, const int* in_sizes, int n_in,
                              void* d_out, int out_size, void* d_ws, size_t ws_size,
                              hipStream_t stream) {
    const float* x     = (const float*)d_in[0];   // [32,256,56,56]
    const float* wgt   = (const float*)d_in[1];   // [256,256,3,3]
    // d_in[2] = bias: cancels exactly in BN, unused
    const float* gamma = (const float*)d_in[3];
    const float* beta  = (const float*)d_in[4];
    float* out = (float*)d_out;

    char* ws = (char*)d_ws;
    int8_t* Bfrag = (int8_t*)(ws + 0);
    float* alpha = (float*)(ws + 589824);
    int*   ssum  = (int*)(ws + 590848);
    unsigned long long* qsum = (unsigned long long*)(ws + 591872);
    u64*   xbits = (u64*)(ws + 593920);
    short* Sarr  = (short*)(ws + 3805184);

    k_prep<<<NPACKBLK + 256, 256, 0, stream>>>(x, wgt, xbits, Bfrag, alpha, ssum, qsum);
    kc_mfma<<<B_ * HBLK, 256, 0, stream>>>(xbits, Bfrag, Sarr, ssum, qsum);
    kb_apply<<<COUT * B_, 256, 0, stream>>>(Sarr, ssum, qsum, alpha, gamma, beta, out);
}

// Round 5
// 275.500 us; speedup vs baseline: 1.0413x; 1.0091x over previous
//
#include <hip/hip_runtime.h>
#include <stdint.h>

typedef unsigned long long u64;
typedef unsigned int u32;
typedef int v4i __attribute__((ext_vector_type(4)));
typedef int v16i __attribute__((ext_vector_type(16)));
typedef short s4v __attribute__((ext_vector_type(4)));
typedef short s8v __attribute__((ext_vector_type(8)));
typedef float f4v __attribute__((ext_vector_type(4)));
typedef u32 u32x4 __attribute__((ext_vector_type(4)));

#define B_    32
#define CIN   256
#define COUT  256
#define H_    56
#define W_    56
#define HW    3136            // H_*W_
#define NPOS  100352          // B_*HW
#define HBLK  28              // H_/2  (two output rows per block)
#define NPACKBLK 784          // (NPOS/4/256) * 8 j2-chunks of 32 channels

// ---- workspace layout (bytes) ----
// 0        : Bfrag i8[wv=4][kk=72][ntl=2][64][16]  589824  (per-wave contiguous streams)
// 589824   : alpha f32[256]           1024
// 590848   : ssum  i32[256]           1024
// 591872   : qsum  u64[256]           2048
// 593920   : xbits u32[8][NPOS]       3211264  (8 channel-planes of 32; ends 3805184)
// 3805184  : S     s16[256][NPOS] CHW-major  51380224 (ends 55185408)

// ---------------- Kernel 1: prep (x bitpack ∪ weight prep), grid-partitioned ----------------
__global__ __launch_bounds__(256) void k_prep(
    const float* __restrict__ x,     // [B, C, H, W]
    const float* __restrict__ wgt,   // [O=256, I=256, 3, 3]
    u32* __restrict__ xbits,         // [8][NPOS] u32 planes (channels 32*j2 .. 32*j2+31)
    int8_t* __restrict__ Bfrag,      // [wv][kk][ntl][lane][16]
    float* __restrict__ alpha,
    int* __restrict__ ssum,
    unsigned long long* __restrict__ qsum)
{
    const int tid = threadIdx.x;

    if (blockIdx.x < NPACKBLK) {
        // ---- pack sign(x): 4 positions per thread, 32 channels per block ----
        // 784 blocks (~3/CU, 12 waves/CU): 2x the TLP of the 64-ch version for
        // the latency-exposed stride-HW float4 reads; 16-deep unrolled loads.
        const int j2 = blockIdx.x / 98;                  // channel chunk (plane)
        const int p4 = (blockIdx.x - j2 * 98) * 256 + tid;
        const int pos0 = p4 * 4;                          // HW % 4 == 0 -> no b crossing
        const int b = pos0 / HW;
        const int hw = pos0 - b * HW;
        const float* xp = x + (size_t)b * CIN * HW + (size_t)j2 * 32 * HW + hw;
        u32 b0 = 0, b1 = 0, b2 = 0, b3 = 0;
#pragma unroll 16
        for (int k = 0; k < 32; ++k) {
            const float4 v = *(const float4*)(xp + (size_t)k * HW);
            b0 |= (u32)(v.x > 0.0f) << k;
            b1 |= (u32)(v.y > 0.0f) << k;
            b2 |= (u32)(v.z > 0.0f) << k;
            b3 |= (u32)(v.w > 0.0f) << k;
        }
        // plane layout: 16B contiguous per thread, 1KB per wave
        u32* xp4 = xbits + (size_t)j2 * NPOS + pos0;
        *(u32x4*)xp4 = u32x4{b0, b1, b2, b3};
        return;
    }

    // ---- weight prep: mean-center, clip, alpha, Bfrag bytes; zero stats ----
    const int o = blockIdx.x - NPACKBLK;
    const int i = tid;                 // input channel
    const int wave = i >> 6, lane = i & 63;
    __shared__ float sred[4][12];

    if (i == 0) { ssum[o] = 0; qsum[o] = 0ULL; }

    float w9[9];
#pragma unroll
    for (int t = 0; t < 9; ++t) w9[t] = wgt[(o * 256 + i) * 9 + t];

    float m[9];
#pragma unroll
    for (int t = 0; t < 9; ++t) m[t] = w9[t];
#pragma unroll
    for (int s = 1; s < 64; s <<= 1)
#pragma unroll
        for (int t = 0; t < 9; ++t) m[t] += __shfl_xor(m[t], s, 64);
    if (lane == 0) {
#pragma unroll
        for (int t = 0; t < 9; ++t) sred[wave][t] = m[t];
    }
    __syncthreads();
#pragma unroll
    for (int t = 0; t < 9; ++t)
        m[t] = (sred[0][t] + sred[1][t] + sred[2][t] + sred[3][t]) * (1.0f / 256.0f);

    float wc[9];
    float asum = 0.0f;
#pragma unroll
    for (int t = 0; t < 9; ++t) {
        float v = w9[t] - m[t];
        v = fminf(fmaxf(v, -1.0f), 1.0f);
        wc[t] = v;
        asum += fabsf(v);
    }
#pragma unroll
    for (int s = 1; s < 64; s <<= 1) asum += __shfl_xor(asum, s, 64);
    __syncthreads();
    if (lane == 0) sred[wave][9] = asum;
    __syncthreads();
    if (i == 0)
        alpha[o] = (sred[0][9] + sred[1][9] + sred[2][9] + sred[3][9]) * (1.0f / 2304.0f);

    // Bfrag[wv][kk][ntl][l][j]: value = sign(wc) for k = kk*32 + (l>>5)*16 + j,
    // tap = k>>8, c = k&255; out-channel o = (wv*2+ntl)*32 + (l&31).
#pragma unroll
    for (int t = 0; t < 9; ++t) {
        const int8_t sv = (wc[t] > 0.0f) ? (int8_t)1 : (int8_t)-1;
        const int kk = t * 8 + (i >> 5);
        const size_t addr =
            ((((size_t)(o >> 6) * 72 + kk) * 2 + ((o >> 5) & 1)) * 64
             + (size_t)(((i >> 4) & 1) * 32 + (o & 31))) * 16 + (i & 15);
        Bfrag[addr] = sv;
    }
}

// ---------------- Kernel 2: implicit-GEMM i8 MFMA conv -> S ([C][NPOS] s16) + stats ----------------
// Block = (b, h-pair): M=128 positions (2 output rows of 56), N=256 channels,
// K=2304 (72 steps of 32). Each wave: 4 A-tiles x 2 B-slices = 8 MFMA/kk,
// reusing the SAME 2KB of B across 128 M (B-stream 16KB/kk/CU, under MFMA time).
// A staged in LDS as ±1 bytes over 4 input rows (58 cols; wp=0/57 zero pad;
// M-pad lanes clamp to col 57 — results discarded). XOR granule swizzle
// (g ^ (wp&15)) breaks the 256B-stride bank pattern AND makes the per-kk read
// address a single v_xor with a literal: addr = P_mt ^ (s<<5), P_mt CSE'd per
// 8-kk tap group. B streamed from per-wave-contiguous Bfrag (L2-resident).
// s_setprio(1) wraps the MFMA cluster (waves are barrier-free/phase-slipped).
// Epilogue: acc -> LDS (A-buffer dead, 256ch x 116sh stride-232B = conflict-free)
// -> 224B-contiguous dwordx4 runs per channel into channel-major S.
// NOTE (R5): reverted to the R3 structure verbatim (known-good, 80.6us median);
// the R4 full-asm counted-wait loop faulted on HW. Per-kk accounting says the
// pipes serialize per-wave at 2 waves/SIMD (register wall: 128 AGPR acc + 128
// VGPR = 256/wave); next lever is B via global_load_lds DMA, not reg-prefetch.
#define MFMA_I8(acc, a, b) \
    asm volatile("v_mfma_i32_32x32x32_i8 %0, %1, %2, %0" : "+a"(acc) : "v"(a), "v"(b))

__global__ __launch_bounds__(256, 2) void kc_mfma(
    const u32* __restrict__ xbits,   // [8][NPOS]
    const int8_t* __restrict__ Bfrag,
    short* __restrict__ S,           // [256][NPOS]
    int* __restrict__ ssum,
    unsigned long long* __restrict__ qsum)
{
    const int blk = blockIdx.x;        // (b, h-pair)
    const int b = blk / HBLK;
    const int h0 = (blk - b * HBLK) * 2;
    const int tid = threadIdx.x;

    __shared__ u32 ldsb[4 * 58 * 64];  // 59392 B -> 2 blocks/CU

    for (int it = tid; it < 4 * 58 * 16; it += 256) {
        const int r = it / 928;              // 58*16, r = 0..3 -> input rows h0-1..h0+2
        const int rem = it - r * 928;
        const int wp = rem >> 4;
        const int g = rem & 15;
        const int hr = h0 - 1 + r;
        const int w_in = wp - 1;
        const bool inb = (hr >= 0) && (hr < H_) && (w_in >= 0) && (w_in < W_);
        u32 chunk16 = 0;
        if (inb) {
            const u32 word = xbits[(size_t)(g >> 1) * NPOS
                                   + (size_t)(b * HW + hr * W_ + w_in)];
            chunk16 = (word >> ((g & 1) * 16)) & 0xFFFFu;
        }
        u32 out4[4];
#pragma unroll
        for (int d = 0; d < 4; ++d) {
            const u32 nib = (chunk16 >> (4 * d)) & 0xFu;
            const u32 m1 = (nib * 0x00204081u) & 0x01010101u;   // bit u -> byte u
            const u32 inv = m1 ^ 0x01010101u;
            out4[d] = inb ? (0x01010101u ^ (inv * 0xFEu)) : 0u; // 1->+1, 0->-1, OOB->0
        }
        const int gs = (g ^ wp) & 15;        // XOR granule swizzle
        u32* dst = &ldsb[((r * 58 + wp) << 6) + gs * 4];
        dst[0] = out4[0]; dst[1] = out4[1]; dst[2] = out4[2]; dst[3] = out4[3];
    }
    __syncthreads();

    const int m0 = tid & 31;           // M row within 32-tile / channel low bits
    const int lh = (tid >> 5) & 1;     // k-half selector
    const int wv = tid >> 6;           // wave id: N cols 64*wv .. 64*wv+63
    const int8_t* smem = (const int8_t*)ldsb;
    const int8_t* Bp = Bfrag + (size_t)wv * 147456 + (size_t)(tid & 63) * 16;

    // mt = 0..3: output row h0 + (mt>>1), w-tile (mt&1)
    auto ldA = [&](int kk, int mt) -> v4i {
        const int tap = kk >> 3, s = kk & 7;   // constants after unroll
        const int dh = tap / 3;
        const int dw = tap - dh * 3;
        const int r = (mt >> 1) + dh;
        // even w-tiles: m0+dw <= 33 < 58, no clamp needed
        const int wpm = (mt & 1) ? min(32 + m0 + dw, 57) : (m0 + dw);
        const int P = ((r * 58 + wpm) << 8) + ((((wpm & 15) ^ lh)) << 4); // CSE per tap
        return *(const v4i*)(smem + (P ^ (s << 5)));   // 1 v_xor per kk
    };
    auto ldB = [&](int kk, int ntl) -> v4i {
        return *(const v4i*)(Bp + (size_t)kk * 2048 + ntl * 1024);
    };

    v16i acc[4][2] = {};
    v4i A[4][2], Bb[2][2];

#pragma unroll
    for (int mt = 0; mt < 4; ++mt) A[mt][0] = ldA(0, mt);
    Bb[0][0] = ldB(0, 0);
    Bb[1][0] = ldB(0, 1);

#pragma unroll
    for (int kk = 0; kk < 72; ++kk) {
        const int cur = kk & 1, nxt = cur ^ 1;
        if (kk < 71) {
#pragma unroll
            for (int mt = 0; mt < 4; ++mt) A[mt][nxt] = ldA(kk + 1, mt);
            Bb[0][nxt] = ldB(kk + 1, 0);
            Bb[1][nxt] = ldB(kk + 1, 1);
        }
        __builtin_amdgcn_s_setprio(1);
#pragma unroll
        for (int mt = 0; mt < 4; ++mt) {
            MFMA_I8(acc[mt][0], A[mt][cur], Bb[0][cur]);
            MFMA_I8(acc[mt][1], A[mt][cur], Bb[1][cur]);
        }
        __builtin_amdgcn_s_setprio(0);
    }

    // drain MFMA pipe before AGPR reads (compiler is blind to asm latency)
    asm volatile("s_nop 7\n\ts_nop 7\n\ts_nop 7"
                 : "+a"(acc[0][0]), "+a"(acc[0][1]), "+a"(acc[1][0]), "+a"(acc[1][1]),
                   "+a"(acc[2][0]), "+a"(acc[2][1]), "+a"(acc[3][0]), "+a"(acc[3][1]));

    // ---- epilogue: stats + pack acc into LDS (A-buffer dead), then coalesced copy ----
    // C/D layout: n = nt*32 + (lane&31); m-in-tile = (reg&3) + 8*(reg>>2) + 4*lh.
    const int n0 = wv * 64 + m0;
    int s0 = 0, s1 = 0, q0 = 0, q1 = 0;

    __syncthreads();                        // all A ds_reads retired; reuse ldsb
    short* eP = (short*)ldsb;               // [c=256][116 shorts] stride 232B

#pragma unroll
    for (int mt = 0; mt < 4; ++mt) {
        const int posb = (mt >> 1) * 56 + ((mt & 1) << 5) + (lh << 2);
        const int nq = (mt & 1) ? 3 : 4;    // odd w-tiles: w 32..55 only (regs < 12)
#pragma unroll
        for (int q = 0; q < nq; ++q) {
            s4v pk0, pk1;
#pragma unroll
            for (int j = 0; j < 4; ++j) {
                const int v0 = acc[mt][0][4 * q + j];
                const int v1 = acc[mt][1][4 * q + j];
                s0 += v0; q0 += v0 * v0; s1 += v1; q1 += v1 * v1;
                pk0[j] = (short)v0;
                pk1[j] = (short)v1;
            }
            const int pq = posb + 8 * q;    // position within the 112-run
            *(s4v*)((char*)eP + n0 * 232 + pq * 2) = pk0;
            *(s4v*)((char*)eP + (n0 + 32) * 232 + pq * 2) = pk1;
        }
    }
    __syncthreads();

    // copy out: per channel a contiguous 224B run (112 shorts = rows h0,h0+1)
    {
        const int l = tid & 63;
        if (l < 56) {
            const int ch2 = l / 14;          // 4 channels x 14 lanes = 224B each
            const int ii = l - ch2 * 14;
            const size_t posb2 = (size_t)b * HW + (size_t)h0 * W_;
#pragma unroll
            for (int t2 = 0; t2 < 16; ++t2) {
                const int cg = wv * 64 + t2 * 4 + ch2;
                const v4i val = *(const v4i*)((const char*)eP + cg * 232 + ii * 16);
                *(v4i*)(S + (size_t)cg * NPOS + posb2 + ii * 8) = val;
            }
        }
    }

    s0 += __shfl_xor(s0, 32, 64); q0 += __shfl_xor(q0, 32, 64);
    s1 += __shfl_xor(s1, 32, 64); q1 += __shfl_xor(q1, 32, 64);
    if (lh == 0) {
        atomicAdd(&ssum[n0], s0);
        atomicAdd(&qsum[n0], (unsigned long long)(long long)q0);
        atomicAdd(&ssum[n0 + 32], s1);
        atomicAdd(&qsum[n0 + 32], (unsigned long long)(long long)q1);
    }
}

// ---------------- Kernel 3: BN finalize + ReLU, pure streaming ----------------
// S is [C][B][HW]; out is [B][C][HW]. One block per (c,b) plane: contiguous
// short8 reads, contiguous float4 writes. No LDS, no transpose.
__global__ __launch_bounds__(256) void kb_apply(
    const short* __restrict__ S,
    const int* __restrict__ ssum,
    const unsigned long long* __restrict__ qsum,
    const float* __restrict__ alpha,
    const float* __restrict__ gamma,
    const float* __restrict__ beta,
    float* __restrict__ out)
{
    const int blk = blockIdx.x;              // c*32 + b  (consecutive blocks stream S)
    const int c = blk >> 5;
    const int b = blk & 31;

    // BN finalize: block-uniform scalars (conv bias cancels exactly in training BN)
    const double N = (double)NPOS;
    const double meanS = (double)ssum[c] / N;
    const double varS = (double)qsum[c] / N - meanS * meanS;
    const double a = (double)alpha[c];
    const double rstd = 1.0 / sqrt(a * a * varS + 1e-5);
    const double g = (double)gamma[c];
    const float scale = (float)(g * a * rstd);
    const float shift = (float)((double)beta[c] - g * a * meanS * rstd);

    const s8v* src = (const s8v*)(S + (size_t)c * NPOS + (size_t)b * HW);
    float* dst = out + ((size_t)(b * COUT + c)) * HW;

    for (int idx = threadIdx.x; idx < HW / 8; idx += 256) {   // 392 short8 chunks
        const s8v v = src[idx];
        f4v o0, o1;
#pragma unroll
        for (int j = 0; j < 4; ++j)
            o0[j] = fmaxf(fmaf((float)v[j], scale, shift), 0.0f);
#pragma unroll
        for (int j = 0; j < 4; ++j)
            o1[j] = fmaxf(fmaf((float)v[4 + j], scale, shift), 0.0f);
        *(f4v*)(dst + idx * 8) = o0;
        *(f4v*)(dst + idx * 8 + 4) = o1;
    }
}

extern "C" void kernel_launch(void* const* d_in, const int* in_sizes, int n_in,
                              void* d_out, int out_size, void* d_ws, size_t ws_size,
                              hipStream_t stream) {
    const float* x     = (const float*)d_in[0];   // [32,256,56,56]
    const float* wgt   = (const float*)d_in[1];   // [256,256,3,3]
    // d_in[2] = bias: cancels exactly in BN, unused
    const float* gamma = (const float*)d_in[3];
    const float* beta  = (const float*)d_in[4];
    float* out = (float*)d_out;

    char* ws = (char*)d_ws;
    int8_t* Bfrag = (int8_t*)(ws + 0);
    float* alpha = (float*)(ws + 589824);
    int*   ssum  = (int*)(ws + 590848);
    unsigned long long* qsum = (unsigned long long*)(ws + 591872);
    u32*   xbits = (u32*)(ws + 593920);
    short* Sarr  = (short*)(ws + 3805184);

    k_prep<<<NPACKBLK + 256, 256, 0, stream>>>(x, wgt, xbits, Bfrag, alpha, ssum, qsum);
    kc_mfma<<<B_ * HBLK, 256, 0, stream>>>(xbits, Bfrag, Sarr, ssum, qsum);
    kb_apply<<<COUT * B_, 256, 0, stream>>>(Sarr, ssum, qsum, alpha, gamma, beta, out);
}